// Round 11
// baseline (252.777 us; speedup 1.0000x reference)
//
#include <hip/hip_runtime.h>

#define D   64
#define H   8
#define DH  8
#define ED  16
#define QK_SCALE 0.35355339059327373f   // 1/sqrt(8)

typedef unsigned int uint_t;

__device__ __forceinline__ void fma4(float4& a, float s, const float4& w) {
    a.x += s * w.x; a.y += s * w.y; a.z += s * w.z; a.w += s * w.w;
}
__device__ __forceinline__ uint_t f2bf(float f) {           // RNE f32->bf16
    uint_t u = __float_as_uint(f);
    return (u + 0x7FFFu + ((u >> 16) & 1u)) >> 16;
}
__device__ __forceinline__ float bf_lo(uint_t u) { return __uint_as_float(u << 16); }
__device__ __forceinline__ float bf_hi(uint_t u) { return __uint_as_float(u & 0xFFFF0000u); }

// keep-half transpose reduce: returns sum over all 8 e-lane-groups of acc[e_self]
__device__ __forceinline__ float khreduce8(const float* acc, int e) {
    int b0 = e & 1, b1 = (e >> 1) & 1, b2 = (e >> 2) & 1;
    float t0[4];
    #pragma unroll
    for (int j = 0; j < 4; ++j) {
        float k = b0 ? acc[2*j+1] : acc[2*j];
        float s = b0 ? acc[2*j]   : acc[2*j+1];
        t0[j] = k + __shfl_xor(s, 8);
    }
    float t1[2];
    #pragma unroll
    for (int j = 0; j < 2; ++j) {
        float k = b1 ? t0[2*j+1] : t0[2*j];
        float s = b1 ? t0[2*j]   : t0[2*j+1];
        t1[j] = k + __shfl_xor(s, 16);
    }
    float k = b2 ? t1[1] : t1[0];
    float s = b2 ? t1[0] : t1[1];
    return k + __shfl_xor(s, 32);
}

// ---------------------------------------------------------------------------
// K1 fused: [proj_qs blocks | csr_hist blocks]
// ---------------------------------------------------------------------------
__global__ __launch_bounds__(256) void proj_qs_hist(
    const float* __restrict__ x,
    const float* __restrict__ Wq, const float* __restrict__ bq,
    const float* __restrict__ Ws, const float* __restrict__ bs,
    const float* __restrict__ We, const float* __restrict__ be,
    float* __restrict__ q, float* __restrict__ xr,
    uint_t* __restrict__ Ap, float* __restrict__ qbe, int N,
    const int* __restrict__ ei, int* __restrict__ cnt, int E, int projBlocks)
{
    __shared__ float sW[2][D * D];          // 32 KB
    __shared__ float sWe[ED * D];           // 4 KB
    __shared__ float sbe[D];
    if (blockIdx.x >= projBlocks) {
        int gid = (blockIdx.x - projBlocks) * 256 + threadIdx.x;
        if (gid < E) atomicAdd(&cnt[ei[E + gid]], 1);
        return;
    }
    {
        for (int t = threadIdx.x; t < D * D; t += 256) {
            sW[0][t] = Wq[t];
            sW[1][t] = Ws[t];
        }
        for (int t = threadIdx.x; t < ED * D; t += 256) sWe[t] = We[t];
        if (threadIdx.x < D) sbe[threadIdx.x] = be[threadIdx.x];
    }
    __syncthreads();

    int cg = (threadIdx.x & 15) * 4;
    float4 vbq = *(const float4*)(bq + cg);
    float4 vbs = *(const float4*)(bs + cg);
    int h  = cg >> 3;
    int hh = (cg >> 2) & 1;

    #pragma unroll 1
    for (int it = 0; it < 4; ++it) {
        int node = blockIdx.x * 64 + it * 16 + (threadIdx.x >> 4);
        if (node >= N) return;

        float4 aq = {0,0,0,0}, as_ = {0,0,0,0};
        const float* xrow = x + (size_t)node * D;

        #pragma unroll
        for (int i = 0; i < D; i += 4) {
            float4 xv = *(const float4*)(xrow + i);
            #pragma unroll
            for (int s = 0; s < 4; ++s) {
                float xs = (&xv.x)[s];
                fma4(aq,  xs, *(const float4*)(&sW[0][(i + s) * D + cg]));
                fma4(as_, xs, *(const float4*)(&sW[1][(i + s) * D + cg]));
            }
        }
        aq.x = (aq.x + vbq.x) * QK_SCALE;
        aq.y = (aq.y + vbq.y) * QK_SCALE;
        aq.z = (aq.z + vbq.z) * QK_SCALE;
        aq.w = (aq.w + vbq.w) * QK_SCALE;
        as_.x += vbs.x; as_.y += vbs.y; as_.z += vbs.z; as_.w += vbs.w;

        size_t o = (size_t)node * D + cg;
        *(float4*)(q  + o) = aq;
        *(float4*)(xr + o) = as_;

        // --- A projection: A[h,i] = sum_dh q[8h+dh]*We[i,8h+dh] ---
        float part[ED];
        #pragma unroll
        for (int i = 0; i < ED; ++i) {
            float pi = 0.f;
            #pragma unroll
            for (int s = 0; s < 4; ++s)
                pi += (&aq.x)[s] * sWe[i * D + cg + s];
            part[i] = pi;
        }
        float qb = 0.f;
        #pragma unroll
        for (int s = 0; s < 4; ++s) qb += (&aq.x)[s] * sbe[cg + s];
        #pragma unroll
        for (int i = 0; i < ED; ++i) part[i] += __shfl_xor(part[i], 1);
        qb += __shfl_xor(qb, 1);

        uint4 apk;
        apk.x = f2bf(part[hh * 8 + 0]) | (f2bf(part[hh * 8 + 1]) << 16);
        apk.y = f2bf(part[hh * 8 + 2]) | (f2bf(part[hh * 8 + 3]) << 16);
        apk.z = f2bf(part[hh * 8 + 4]) | (f2bf(part[hh * 8 + 5]) << 16);
        apk.w = f2bf(part[hh * 8 + 6]) | (f2bf(part[hh * 8 + 7]) << 16);
        *(uint4*)(Ap + (size_t)node * 64 + h * 8 + hh * 4) = apk;
        if (hh == 0) qbe[(size_t)node * 8 + h] = qb;
    }
}

// ---------------------------------------------------------------------------
// K2 fused: [proj_kv blocks | scan_a blocks]
// ---------------------------------------------------------------------------
__global__ __launch_bounds__(256) void proj_kv_scana(
    const float* __restrict__ x,
    const float* __restrict__ Wk, const float* __restrict__ bk,
    const float* __restrict__ Wv, const float* __restrict__ bv,
    uint_t* __restrict__ kvp, int N, int kvBlocks,
    const int* __restrict__ cnt, int* __restrict__ bsum)
{
    __shared__ float sW[2][D * D];          // 32 KB
    __shared__ int red[256];
    if (blockIdx.x >= kvBlocks) {
        int t = threadIdx.x;
        int i = (blockIdx.x - kvBlocks) * 256 + t;
        red[t] = (i < N) ? cnt[i] : 0;
        __syncthreads();
        for (int s = 128; s > 0; s >>= 1) {
            if (t < s) red[t] += red[t + s];
            __syncthreads();
        }
        if (t == 0) bsum[blockIdx.x - kvBlocks] = red[0];
        return;
    }
    for (int t = threadIdx.x; t < D * D; t += 256) {
        sW[0][t] = Wk[t];
        sW[1][t] = Wv[t];
    }
    __syncthreads();

    int cg = (threadIdx.x & 15) * 4;
    float4 vbk = *(const float4*)(bk + cg);
    float4 vbv = *(const float4*)(bv + cg);

    #pragma unroll 1
    for (int it = 0; it < 4; ++it) {
        int node = blockIdx.x * 64 + it * 16 + (threadIdx.x >> 4);
        if (node >= N) return;

        float4 ak = {0,0,0,0}, av = {0,0,0,0};
        const float* xrow = x + (size_t)node * D;

        #pragma unroll
        for (int i = 0; i < D; i += 4) {
            float4 xv = *(const float4*)(xrow + i);
            #pragma unroll
            for (int s = 0; s < 4; ++s) {
                float xs = (&xv.x)[s];
                fma4(ak, xs, *(const float4*)(&sW[0][(i + s) * D + cg]));
                fma4(av, xs, *(const float4*)(&sW[1][(i + s) * D + cg]));
            }
        }
        ak.x += vbk.x; ak.y += vbk.y; ak.z += vbk.z; ak.w += vbk.w;
        av.x += vbv.x; av.y += vbv.y; av.z += vbv.z; av.w += vbv.w;

        uint4 pkv;
        pkv.x = f2bf(ak.x) | (f2bf(av.x) << 16);
        pkv.y = f2bf(ak.y) | (f2bf(av.y) << 16);
        pkv.z = f2bf(ak.z) | (f2bf(av.z) << 16);
        pkv.w = f2bf(ak.w) | (f2bf(av.w) << 16);
        *(uint4*)(kvp + (size_t)node * D + cg) = pkv;
    }
}

// ---------------------------------------------------------------------------
// scan_c merged with scan_b: every block redundantly scans the block sums.
// ---------------------------------------------------------------------------
__global__ __launch_bounds__(256) void scan_c(
    const int* __restrict__ cnt, const int* __restrict__ bsum,
    int* __restrict__ row_start, int* __restrict__ cursor, int N, int E, int nb)
{
    __shared__ int sb[256];
    __shared__ int sh[256];
    int t = threadIdx.x;
    int bv = (t < nb) ? bsum[t] : 0;
    sb[t] = bv;
    __syncthreads();
    for (int s = 1; s < 256; s <<= 1) {
        int a = (t >= s) ? sb[t - s] : 0;
        __syncthreads();
        sb[t] += a;
        __syncthreads();
    }
    int boff = sb[blockIdx.x] - bsum[blockIdx.x];   // exclusive block offset

    int i = blockIdx.x * 256 + t;
    int v = (i < N) ? cnt[i] : 0;
    sh[t] = v;
    __syncthreads();
    for (int s = 1; s < 256; s <<= 1) {
        int a = (t >= s) ? sh[t - s] : 0;
        __syncthreads();
        sh[t] += a;
        __syncthreads();
    }
    int excl = sh[t] - v + boff;
    if (i < N) { row_start[i] = excl; cursor[i] = excl; }
    if (i == N - 1) row_start[N] = E;
}

// ---------------------------------------------------------------------------
// K5: payload scatter. srcs_s[pos] + ea_s[pos] (bf16 row) in CSR order.
// ---------------------------------------------------------------------------
__global__ __launch_bounds__(256) void csr_scatter(
    const int* __restrict__ ei, const float4* __restrict__ ea4,
    int* __restrict__ cursor, int* __restrict__ srcs_s,
    uint_t* __restrict__ ea_s, int E)
{
    int gid = blockIdx.x * 256 + threadIdx.x;
    if (gid >= E) return;
    int src = ei[gid];
    int dst = ei[E + gid];
    float4 r0 = ea4[(size_t)gid * 4 + 0];
    float4 r1 = ea4[(size_t)gid * 4 + 1];
    float4 r2 = ea4[(size_t)gid * 4 + 2];
    float4 r3 = ea4[(size_t)gid * 4 + 3];
    int pos = atomicAdd(&cursor[dst], 1);
    srcs_s[pos] = src;
    uint4 p0, p1;
    p0.x = f2bf(r0.x) | (f2bf(r0.y) << 16);
    p0.y = f2bf(r0.z) | (f2bf(r0.w) << 16);
    p0.z = f2bf(r1.x) | (f2bf(r1.y) << 16);
    p0.w = f2bf(r1.z) | (f2bf(r1.w) << 16);
    p1.x = f2bf(r2.x) | (f2bf(r2.y) << 16);
    p1.y = f2bf(r2.z) | (f2bf(r2.w) << 16);
    p1.z = f2bf(r3.x) | (f2bf(r3.y) << 16);
    p1.w = f2bf(r3.z) | (f2bf(r3.w) << 16);
    *(uint4*)(ea_s + (size_t)pos * 8)     = p0;
    *(uint4*)(ea_s + (size_t)pos * 8 + 4) = p1;
}

// ---------------------------------------------------------------------------
// K6: pull gather, (edge-slot x head) lanes, 2-NODE ILP per wave.
//     Mixed layout end-to-end (no final permute). Masked unified batch loop.
// ---------------------------------------------------------------------------
#define GBODY(rs_, deg_, qa_, qb_, aA_, aB_, qbe_, acc_, sv_, den_)            \
{                                                                              \
    int eidx = j0 + e;                                                         \
    bool valid = eidx < (deg_);                                                \
    int ce = valid ? eidx : 0;                                                 \
    int src = srcs_s[(rs_) + ce];                                              \
    const uint4* kp = (const uint4*)(kvp + (size_t)src * 64 + h * 8);          \
    uint4 k0 = kp[0], k1 = kp[1];                                              \
    const uint4* ep = (const uint4*)(ea_s + (size_t)((rs_) + ce) * 8);         \
    uint4 u0 = ep[0], u1 = ep[1];                                              \
    float c = qbe_;                                                            \
    c += qa_.x * bf_lo(k0.x) + qa_.y * bf_lo(k0.y)                             \
       + qa_.z * bf_lo(k0.z) + qa_.w * bf_lo(k0.w);                            \
    c += qb_.x * bf_lo(k1.x) + qb_.y * bf_lo(k1.y)                             \
       + qb_.z * bf_lo(k1.z) + qb_.w * bf_lo(k1.w);                            \
    float ex[ED];                                                              \
    ex[0]=bf_lo(u0.x); ex[1]=bf_hi(u0.x); ex[2]=bf_lo(u0.y); ex[3]=bf_hi(u0.y);\
    ex[4]=bf_lo(u0.z); ex[5]=bf_hi(u0.z); ex[6]=bf_lo(u0.w); ex[7]=bf_hi(u0.w);\
    ex[8]=bf_lo(u1.x); ex[9]=bf_hi(u1.x); ex[10]=bf_lo(u1.y);ex[11]=bf_hi(u1.y);\
    ex[12]=bf_lo(u1.z);ex[13]=bf_hi(u1.z);ex[14]=bf_lo(u1.w);ex[15]=bf_hi(u1.w);\
    c += ex[0]*bf_lo(aA_.x) + ex[1]*bf_hi(aA_.x) + ex[2]*bf_lo(aA_.y)          \
       + ex[3]*bf_hi(aA_.y) + ex[4]*bf_lo(aA_.z) + ex[5]*bf_hi(aA_.z)          \
       + ex[6]*bf_lo(aA_.w) + ex[7]*bf_hi(aA_.w);                              \
    c += ex[8]*bf_lo(aB_.x) + ex[9]*bf_hi(aB_.x) + ex[10]*bf_lo(aB_.y)         \
       + ex[11]*bf_hi(aB_.y) + ex[12]*bf_lo(aB_.z) + ex[13]*bf_hi(aB_.z)       \
       + ex[14]*bf_lo(aB_.w) + ex[15]*bf_hi(aB_.w);                            \
    float p = valid ? __expf(c) : 0.f;                                         \
    den_ += p;                                                                 \
    acc_[0]+=p*bf_hi(k0.x); acc_[1]+=p*bf_hi(k0.y);                            \
    acc_[2]+=p*bf_hi(k0.z); acc_[3]+=p*bf_hi(k0.w);                            \
    acc_[4]+=p*bf_hi(k1.x); acc_[5]+=p*bf_hi(k1.y);                            \
    acc_[6]+=p*bf_hi(k1.z); acc_[7]+=p*bf_hi(k1.w);                            \
    _Pragma("unroll")                                                          \
    for (int i = 0; i < ED; ++i) sv_[i] += p * ex[i];                          \
}

__global__ __launch_bounds__(256, 3) void node_gather(
    const int*   __restrict__ row_start, // [N+1]
    const int*   __restrict__ srcs_s,    // [E] CSR-ordered src
    const uint_t* __restrict__ ea_s,     // [E*8] CSR-ordered bf16x2
    const float* __restrict__ We, const float* __restrict__ be,
    const float* __restrict__ q, const uint_t* __restrict__ kvp,
    const float* __restrict__ xr,
    const uint_t* __restrict__ Ap, const float* __restrict__ qbe,
    const float* __restrict__ Wbeta,
    float* __restrict__ out, float* __restrict__ S1p, float* __restrict__ S2p,
    int N)
{
    __shared__ float l1[4][D];
    __shared__ float l2[4][D];
    int lane = threadIdx.x & 63;
    int w    = threadIdx.x >> 6;
    int h    = lane & 7;             // head owned by this lane
    int e    = lane >> 3;            // edge slot within batch
    int cmix = h * 8 + e;            // this lane's output column

    float rWe[ED];
    #pragma unroll
    for (int i = 0; i < ED; ++i) rWe[i] = We[i * D + cmix];
    float bev = be[cmix];
    float wb0 = Wbeta[cmix], wb1 = Wbeta[D + cmix], wb2 = Wbeta[2 * D + cmix];

    float s1bn = 0.f, s2bn = 0.f;
    int stride  = gridDim.x * 4;
    int stride2 = stride * 2;

    for (int n0 = blockIdx.x * 4 + w; n0 < N; n0 += stride2) {
        int n1   = n0 + stride;
        bool has1 = n1 < N;
        int n1c  = has1 ? n1 : n0;

        int rs0 = row_start[n0], deg0 = row_start[n0 + 1] - rs0;
        int rs1 = row_start[n1c];
        int deg1 = has1 ? (row_start[n1c + 1] - rs1) : 0;

        const float* qp0 = q + (size_t)n0 * D + h * 8;
        float4 qa0 = *(const float4*)qp0, qb0 = *(const float4*)(qp0 + 4);
        const float* qp1 = q + (size_t)n1c * D + h * 8;
        float4 qa1 = *(const float4*)qp1, qb1 = *(const float4*)(qp1 + 4);

        const uint4* ap0 = (const uint4*)(Ap + (size_t)n0 * 64 + h * 8);
        uint4 aA0 = ap0[0], aB0 = ap0[1];
        const uint4* ap1 = (const uint4*)(Ap + (size_t)n1c * 64 + h * 8);
        uint4 aA1 = ap1[0], aB1 = ap1[1];

        float qbe0 = qbe[(size_t)n0 * 8 + h];
        float qbe1 = qbe[(size_t)n1c * 8 + h];

        float acc0[8] = {0,0,0,0,0,0,0,0};
        float acc1[8] = {0,0,0,0,0,0,0,0};
        float sv0[ED] = {0,0,0,0,0,0,0,0,0,0,0,0,0,0,0,0};
        float sv1[ED] = {0,0,0,0,0,0,0,0,0,0,0,0,0,0,0,0};
        float den0 = 0.f, den1 = 0.f;

        int nbmax = deg0 > deg1 ? deg0 : deg1;
        for (int j0 = 0; j0 < nbmax; j0 += 8) {
            if (j0 < deg0) GBODY(rs0, deg0, qa0, qb0, aA0, aB0, qbe0, acc0, sv0, den0)
            if (j0 < deg1) GBODY(rs1, deg1, qa1, qb1, aA1, aB1, qbe1, acc1, sv1, den1)
        }

        // interleaved reduces (two independent chains)
        #pragma unroll
        for (int m = 8; m <= 32; m <<= 1) {
            den0 += __shfl_xor(den0, m);
            den1 += __shfl_xor(den1, m);
            #pragma unroll
            for (int i = 0; i < ED; ++i) {
                sv0[i] += __shfl_xor(sv0[i], m);
                sv1[i] += __shfl_xor(sv1[i], m);
            }
        }
        float vs0 = khreduce8(acc0, e);
        float vs1 = khreduce8(acc1, e);

        float es0 = 0.f, es1 = 0.f;
        #pragma unroll
        for (int i = 0; i < ED; ++i) {
            es0 += rWe[i] * sv0[i];
            es1 += rWe[i] * sv1[i];
        }

        float o0 = (vs0 + es0 + bev * den0) / (den0 + 1e-16f);
        float o1 = (vs1 + es1 + bev * den1) / (den1 + 1e-16f);

        float xr0 = xr[(size_t)n0 * D + cmix];
        float xr1 = xr[(size_t)n1c * D + cmix];
        float tb0 = o0 * wb0 + xr0 * wb1 + (o0 - xr0) * wb2;
        float tb1 = o1 * wb0 + xr1 * wb1 + (o1 - xr1) * wb2;
        #pragma unroll
        for (int s = 1; s < 64; s <<= 1) {
            tb0 += __shfl_xor(tb0, s);
            tb1 += __shfl_xor(tb1, s);
        }
        float g0 = 1.f / (1.f + __expf(-tb0));
        float o20 = g0 * xr0 + (1.f - g0) * o0;
        out[(size_t)n0 * D + cmix] = o20;
        s1bn += o20; s2bn += o20 * o20;
        if (has1) {
            float g1 = 1.f / (1.f + __expf(-tb1));
            float o21 = g1 * xr1 + (1.f - g1) * o1;
            out[(size_t)n1 * D + cmix] = o21;
            s1bn += o21; s2bn += o21 * o21;
        }
    }

    l1[w][cmix] = s1bn; l2[w][cmix] = s2bn;
    __syncthreads();
    if (threadIdx.x < D) {
        float a = l1[0][threadIdx.x] + l1[1][threadIdx.x]
                + l1[2][threadIdx.x] + l1[3][threadIdx.x];
        float b = l2[0][threadIdx.x] + l2[1][threadIdx.x]
                + l2[2][threadIdx.x] + l2[3][threadIdx.x];
        unsafeAtomicAdd(&S1p[threadIdx.x * 64], a);
        unsafeAtomicAdd(&S2p[threadIdx.x * 64], b);
    }
}

// ---------------------------------------------------------------------------
// K7: batchnorm finalize + apply + LeakyReLU, float4 in place on d_out.
// ---------------------------------------------------------------------------
__global__ __launch_bounds__(256) void bn_apply(
    float4* __restrict__ out, const float* __restrict__ S1p,
    const float* __restrict__ S2p, const float* __restrict__ gamma,
    const float* __restrict__ beta, int total4, float invN)
{
    int gid = blockIdx.x * 256 + threadIdx.x;
    if (gid >= total4) return;
    int col = (gid & 15) * 4;
    float4 g4 = *(const float4*)(gamma + col);
    float4 b4 = *(const float4*)(beta + col);
    float4 y  = out[gid];
    #pragma unroll
    for (int j = 0; j < 4; ++j) {
        float mean = S1p[(col + j) * 64] * invN;
        float var  = S2p[(col + j) * 64] * invN - mean * mean;
        float sc   = (&g4.x)[j] * rsqrtf(var + 1e-5f);
        float sh   = (&b4.x)[j] - mean * sc;
        float tv   = (&y.x)[j] * sc + sh;
        (&y.x)[j]  = (tv >= 0.f) ? tv : 0.01f * tv;
    }
    out[gid] = y;
}

// ---------------------------------------------------------------------------
extern "C" void kernel_launch(void* const* d_in, const int* in_sizes, int n_in,
                              void* d_out, int out_size, void* d_ws, size_t ws_size,
                              hipStream_t stream)
{
    const float* x     = (const float*)d_in[0];
    const int*   ei    = (const int*)  d_in[1];
    const float* ea    = (const float*)d_in[2];
    const float* Wq    = (const float*)d_in[3];
    const float* bq    = (const float*)d_in[4];
    const float* Wk    = (const float*)d_in[5];
    const float* bk    = (const float*)d_in[6];
    const float* Wv    = (const float*)d_in[7];
    const float* bv    = (const float*)d_in[8];
    const float* We    = (const float*)d_in[9];
    const float* be    = (const float*)d_in[10];
    const float* Wskip = (const float*)d_in[11];
    const float* bskip = (const float*)d_in[12];
    const float* Wbeta = (const float*)d_in[13];
    const float* gamma = (const float*)d_in[14];
    const float* betab = (const float*)d_in[15];

    int N = in_sizes[0] / D;   // 50000
    int E = in_sizes[1] / 2;   // 800000

    // ws layout (uint units); total ~82.0 MB
    int*    ws        = (int*)d_ws;
    int*    cnt       = ws;                         // 50000 (also scatter cursor)
    float*  S1p       = (float*)(ws + 50000);       // 4096 padded col sums
    float*  S2p       = (float*)(ws + 54096);       // 4096
    int*    row_start = ws + 58192;                 // 50004
    int*    bsum      = ws + 108240;                // 256 (16B aligned)
    int*    srcs_s    = ws + 108544;                // 800000
    uint_t* ea_s      = (uint_t*)(ws + 908544);     // 6400000
    uint_t* kvp       = (uint_t*)(ws + 7308544);    // 3200000
    float*  q         = (float*)(ws + 10508544);    // 3200000
    float*  xr        = (float*)(ws + 13708544);    // 3200000
    uint_t* Ap        = (uint_t*)(ws + 16908544);   // 3200000
    float*  qbe       = (float*)(ws + 20108544);    // 400000

    // zero cnt + S1p + S2p (contiguous)
    hipMemsetAsync(d_ws, 0, (size_t)58192 * sizeof(int), stream);

    int projB = (N + 63) / 64;      // 782
    int histB = (E + 255) / 256;    // 3125
    proj_qs_hist<<<projB + histB, 256, 0, stream>>>(
        x, Wq, bq, Wskip, bskip, We, be,
        q, xr, Ap, qbe, N, ei, cnt, E, projB);

    int scanB = (N + 255) / 256;    // 196
    proj_kv_scana<<<projB + scanB, 256, 0, stream>>>(
        x, Wk, bk, Wv, bv, kvp, N, projB, cnt, bsum);

    scan_c<<<scanB, 256, 0, stream>>>(cnt, bsum, row_start, cnt, N, E, scanB);

    csr_scatter<<<(E + 255) / 256, 256, 0, stream>>>(
        ei, (const float4*)ea, cnt, srcs_s, ea_s, E);

    node_gather<<<1024, 256, 0, stream>>>(
        row_start, srcs_s, ea_s, We, be, q, kvp, xr, Ap, qbe, Wbeta,
        (float*)d_out, S1p, S2p, N);

    bn_apply<<<(N * 16 + 255) / 256, 256, 0, stream>>>(
        (float4*)d_out, S1p, S2p, gamma, betab, N * 16, 1.0f / (float)N);
}

// Round 12
// 207.999 us; speedup vs baseline: 1.2153x; 1.2153x over previous
//
#include <hip/hip_runtime.h>

#define D   64
#define H   8
#define DH  8
#define ED  16
#define QK_SCALE 0.35355339059327373f   // 1/sqrt(8)

typedef unsigned int uint_t;

__device__ __forceinline__ void fma4(float4& a, float s, const float4& w) {
    a.x += s * w.x; a.y += s * w.y; a.z += s * w.z; a.w += s * w.w;
}
__device__ __forceinline__ uint_t f2bf(float f) {           // RNE f32->bf16
    uint_t u = __float_as_uint(f);
    return (u + 0x7FFFu + ((u >> 16) & 1u)) >> 16;
}
__device__ __forceinline__ float bf_lo(uint_t u) { return __uint_as_float(u << 16); }
__device__ __forceinline__ float bf_hi(uint_t u) { return __uint_as_float(u & 0xFFFF0000u); }

// keep-half transpose reduce: lane (e,h) ends with sum over e' of acc_e'[e]
__device__ __forceinline__ float khreduce8(const float* acc, int e) {
    int b0 = e & 1, b1 = (e >> 1) & 1, b2 = (e >> 2) & 1;
    float t0[4];
    #pragma unroll
    for (int j = 0; j < 4; ++j) {
        float k = b0 ? acc[2*j+1] : acc[2*j];
        float s = b0 ? acc[2*j]   : acc[2*j+1];
        t0[j] = k + __shfl_xor(s, 8);
    }
    float t1[2];
    #pragma unroll
    for (int j = 0; j < 2; ++j) {
        float k = b1 ? t0[2*j+1] : t0[2*j];
        float s = b1 ? t0[2*j]   : t0[2*j+1];
        t1[j] = k + __shfl_xor(s, 16);
    }
    float k = b2 ? t1[1] : t1[0];
    float s = b2 ? t1[0] : t1[1];
    return k + __shfl_xor(s, 32);
}

// ---------------------------------------------------------------------------
// K1 fused: [proj_qs blocks | csr_hist blocks]
// ---------------------------------------------------------------------------
__global__ __launch_bounds__(256) void proj_qs_hist(
    const float* __restrict__ x,
    const float* __restrict__ Wq, const float* __restrict__ bq,
    const float* __restrict__ Ws, const float* __restrict__ bs,
    const float* __restrict__ We, const float* __restrict__ be,
    float* __restrict__ q, float* __restrict__ xr,
    uint_t* __restrict__ Ap, float* __restrict__ qbe, int N,
    const int* __restrict__ ei, int* __restrict__ cnt, int E, int projBlocks)
{
    __shared__ float sW[2][D * D];          // 32 KB
    __shared__ float sWe[ED * D];           // 4 KB
    __shared__ float sbe[D];
    if (blockIdx.x >= projBlocks) {
        int gid = (blockIdx.x - projBlocks) * 256 + threadIdx.x;
        if (gid < E) atomicAdd(&cnt[ei[E + gid]], 1);
        return;
    }
    {
        for (int t = threadIdx.x; t < D * D; t += 256) {
            sW[0][t] = Wq[t];
            sW[1][t] = Ws[t];
        }
        for (int t = threadIdx.x; t < ED * D; t += 256) sWe[t] = We[t];
        if (threadIdx.x < D) sbe[threadIdx.x] = be[threadIdx.x];
    }
    __syncthreads();

    int cg = (threadIdx.x & 15) * 4;
    float4 vbq = *(const float4*)(bq + cg);
    float4 vbs = *(const float4*)(bs + cg);
    int h  = cg >> 3;
    int hh = (cg >> 2) & 1;

    #pragma unroll 1
    for (int it = 0; it < 4; ++it) {
        int node = blockIdx.x * 64 + it * 16 + (threadIdx.x >> 4);
        if (node >= N) return;

        float4 aq = {0,0,0,0}, as_ = {0,0,0,0};
        const float* xrow = x + (size_t)node * D;

        #pragma unroll
        for (int i = 0; i < D; i += 4) {
            float4 xv = *(const float4*)(xrow + i);
            #pragma unroll
            for (int s = 0; s < 4; ++s) {
                float xs = (&xv.x)[s];
                fma4(aq,  xs, *(const float4*)(&sW[0][(i + s) * D + cg]));
                fma4(as_, xs, *(const float4*)(&sW[1][(i + s) * D + cg]));
            }
        }
        aq.x = (aq.x + vbq.x) * QK_SCALE;
        aq.y = (aq.y + vbq.y) * QK_SCALE;
        aq.z = (aq.z + vbq.z) * QK_SCALE;
        aq.w = (aq.w + vbq.w) * QK_SCALE;
        as_.x += vbs.x; as_.y += vbs.y; as_.z += vbs.z; as_.w += vbs.w;

        size_t o = (size_t)node * D + cg;
        *(float4*)(q  + o) = aq;
        *(float4*)(xr + o) = as_;

        // --- A projection: A[h,i] = sum_dh q[8h+dh]*We[i,8h+dh] ---
        float part[ED];
        #pragma unroll
        for (int i = 0; i < ED; ++i) {
            float pi = 0.f;
            #pragma unroll
            for (int s = 0; s < 4; ++s)
                pi += (&aq.x)[s] * sWe[i * D + cg + s];
            part[i] = pi;
        }
        float qb = 0.f;
        #pragma unroll
        for (int s = 0; s < 4; ++s) qb += (&aq.x)[s] * sbe[cg + s];
        #pragma unroll
        for (int i = 0; i < ED; ++i) part[i] += __shfl_xor(part[i], 1);
        qb += __shfl_xor(qb, 1);

        uint4 apk;
        apk.x = f2bf(part[hh * 8 + 0]) | (f2bf(part[hh * 8 + 1]) << 16);
        apk.y = f2bf(part[hh * 8 + 2]) | (f2bf(part[hh * 8 + 3]) << 16);
        apk.z = f2bf(part[hh * 8 + 4]) | (f2bf(part[hh * 8 + 5]) << 16);
        apk.w = f2bf(part[hh * 8 + 6]) | (f2bf(part[hh * 8 + 7]) << 16);
        *(uint4*)(Ap + (size_t)node * 64 + h * 8 + hh * 4) = apk;
        if (hh == 0) qbe[(size_t)node * 8 + h] = qb;
    }
}

// ---------------------------------------------------------------------------
// K2 fused: [proj_kv blocks | scan_a blocks]
// ---------------------------------------------------------------------------
__global__ __launch_bounds__(256) void proj_kv_scana(
    const float* __restrict__ x,
    const float* __restrict__ Wk, const float* __restrict__ bk,
    const float* __restrict__ Wv, const float* __restrict__ bv,
    uint_t* __restrict__ kvp, int N, int kvBlocks,
    const int* __restrict__ cnt, int* __restrict__ bsum)
{
    __shared__ float sW[2][D * D];          // 32 KB
    __shared__ int red[256];
    if (blockIdx.x >= kvBlocks) {
        int t = threadIdx.x;
        int i = (blockIdx.x - kvBlocks) * 256 + t;
        red[t] = (i < N) ? cnt[i] : 0;
        __syncthreads();
        for (int s = 128; s > 0; s >>= 1) {
            if (t < s) red[t] += red[t + s];
            __syncthreads();
        }
        if (t == 0) bsum[blockIdx.x - kvBlocks] = red[0];
        return;
    }
    for (int t = threadIdx.x; t < D * D; t += 256) {
        sW[0][t] = Wk[t];
        sW[1][t] = Wv[t];
    }
    __syncthreads();

    int cg = (threadIdx.x & 15) * 4;
    float4 vbk = *(const float4*)(bk + cg);
    float4 vbv = *(const float4*)(bv + cg);

    #pragma unroll 1
    for (int it = 0; it < 4; ++it) {
        int node = blockIdx.x * 64 + it * 16 + (threadIdx.x >> 4);
        if (node >= N) return;

        float4 ak = {0,0,0,0}, av = {0,0,0,0};
        const float* xrow = x + (size_t)node * D;

        #pragma unroll
        for (int i = 0; i < D; i += 4) {
            float4 xv = *(const float4*)(xrow + i);
            #pragma unroll
            for (int s = 0; s < 4; ++s) {
                float xs = (&xv.x)[s];
                fma4(ak, xs, *(const float4*)(&sW[0][(i + s) * D + cg]));
                fma4(av, xs, *(const float4*)(&sW[1][(i + s) * D + cg]));
            }
        }
        ak.x += vbk.x; ak.y += vbk.y; ak.z += vbk.z; ak.w += vbk.w;
        av.x += vbv.x; av.y += vbv.y; av.z += vbv.z; av.w += vbv.w;

        uint4 pkv;
        pkv.x = f2bf(ak.x) | (f2bf(av.x) << 16);
        pkv.y = f2bf(ak.y) | (f2bf(av.y) << 16);
        pkv.z = f2bf(ak.z) | (f2bf(av.z) << 16);
        pkv.w = f2bf(ak.w) | (f2bf(av.w) << 16);
        *(uint4*)(kvp + (size_t)node * D + cg) = pkv;
    }
}

// ---------------------------------------------------------------------------
// scan_c (merged with scan_b): every block redundantly scans the block sums.
// ---------------------------------------------------------------------------
__global__ __launch_bounds__(256) void scan_c(
    const int* __restrict__ cnt, const int* __restrict__ bsum,
    int* __restrict__ row_start, int* __restrict__ cursor, int N, int E, int nb)
{
    __shared__ int sb[256];
    __shared__ int sh[256];
    int t = threadIdx.x;
    int bv = (t < nb) ? bsum[t] : 0;
    sb[t] = bv;
    __syncthreads();
    for (int s = 1; s < 256; s <<= 1) {
        int a = (t >= s) ? sb[t - s] : 0;
        __syncthreads();
        sb[t] += a;
        __syncthreads();
    }
    int boff = sb[blockIdx.x] - bsum[blockIdx.x];   // exclusive block offset

    int i = blockIdx.x * 256 + t;
    int v = (i < N) ? cnt[i] : 0;
    sh[t] = v;
    __syncthreads();
    for (int s = 1; s < 256; s <<= 1) {
        int a = (t >= s) ? sh[t - s] : 0;
        __syncthreads();
        sh[t] += a;
        __syncthreads();
    }
    int excl = sh[t] - v + boff;
    if (i < N) { row_start[i] = excl; cursor[i] = excl; }
    if (i == N - 1) row_start[N] = E;
}

// ---------------------------------------------------------------------------
// K5: payload scatter. srcs_s[pos] + ea_s[pos] (bf16 row) in CSR order.
// ---------------------------------------------------------------------------
__global__ __launch_bounds__(256) void csr_scatter(
    const int* __restrict__ ei, const float4* __restrict__ ea4,
    int* __restrict__ cursor, int* __restrict__ srcs_s,
    uint_t* __restrict__ ea_s, int E)
{
    int gid = blockIdx.x * 256 + threadIdx.x;
    if (gid >= E) return;
    int src = ei[gid];
    int dst = ei[E + gid];
    float4 r0 = ea4[(size_t)gid * 4 + 0];
    float4 r1 = ea4[(size_t)gid * 4 + 1];
    float4 r2 = ea4[(size_t)gid * 4 + 2];
    float4 r3 = ea4[(size_t)gid * 4 + 3];
    int pos = atomicAdd(&cursor[dst], 1);
    srcs_s[pos] = src;
    uint4 p0, p1;
    p0.x = f2bf(r0.x) | (f2bf(r0.y) << 16);
    p0.y = f2bf(r0.z) | (f2bf(r0.w) << 16);
    p0.z = f2bf(r1.x) | (f2bf(r1.y) << 16);
    p0.w = f2bf(r1.z) | (f2bf(r1.w) << 16);
    p1.x = f2bf(r2.x) | (f2bf(r2.y) << 16);
    p1.y = f2bf(r2.z) | (f2bf(r2.w) << 16);
    p1.z = f2bf(r3.x) | (f2bf(r3.y) << 16);
    p1.w = f2bf(r3.z) | (f2bf(r3.w) << 16);
    *(uint4*)(ea_s + (size_t)pos * 8)     = p0;
    *(uint4*)(ea_s + (size_t)pos * 8 + 4) = p1;
}

// ---------------------------------------------------------------------------
// K6: pull gather, (edge-slot x head) lanes, 1 node/wave (R10 shape),
//     khreduce8 + mixed-layout epilogue + next-batch src prefetch.
// ---------------------------------------------------------------------------
__global__ __launch_bounds__(256, 4) void node_gather(
    const int*   __restrict__ row_start, // [N+1]
    const int*   __restrict__ srcs_s,    // [E] CSR-ordered src
    const uint_t* __restrict__ ea_s,     // [E*8] CSR-ordered bf16x2
    const float* __restrict__ We, const float* __restrict__ be,
    const float* __restrict__ q, const uint_t* __restrict__ kvp,
    const float* __restrict__ xr,
    const uint_t* __restrict__ Ap, const float* __restrict__ qbe,
    const float* __restrict__ Wbeta,
    float* __restrict__ out, float* __restrict__ S1p, float* __restrict__ S2p,
    int N)
{
    __shared__ float l1[4][D];
    __shared__ float l2[4][D];
    int lane = threadIdx.x & 63;
    int w    = threadIdx.x >> 6;
    int h    = lane & 7;             // head owned by this lane
    int e    = lane >> 3;            // edge slot within batch
    int cmix = h * 8 + e;            // this lane's output column

    float rWe[ED];
    #pragma unroll
    for (int i = 0; i < ED; ++i) rWe[i] = We[i * D + cmix];
    float bev = be[cmix];
    float wb0 = Wbeta[cmix], wb1 = Wbeta[D + cmix], wb2 = Wbeta[2 * D + cmix];

    float s1bn = 0.f, s2bn = 0.f;
    int stride = gridDim.x * 4;

    for (int nid = blockIdx.x * 4 + w; nid < N; nid += stride) {
        int rs  = row_start[nid];
        int deg = row_start[nid + 1] - rs;

        const float* qp = q + (size_t)nid * D + h * 8;
        float4 q0 = *(const float4*)qp;
        float4 q1 = *(const float4*)(qp + 4);
        const uint4* app = (const uint4*)(Ap + (size_t)nid * 64 + h * 8);
        uint4 au0 = app[0], au1 = app[1];
        float a16[ED];
        #pragma unroll
        for (int j = 0; j < 4; ++j) {
            a16[j * 2]         = bf_lo((&au0.x)[j]);
            a16[j * 2 + 1]     = bf_hi((&au0.x)[j]);
            a16[8 + j * 2]     = bf_lo((&au1.x)[j]);
            a16[8 + j * 2 + 1] = bf_hi((&au1.x)[j]);
        }
        float qbeh = qbe[(size_t)nid * 8 + h];

        float acc[8] = {0,0,0,0,0,0,0,0};
        float sv[ED] = {0,0,0,0,0,0,0,0,0,0,0,0,0,0,0,0};
        float den = 0.f;

        // prefetch first batch's src
        int src_next = (e < deg) ? srcs_s[rs + e] : 0;

        for (int j0 = 0; j0 < deg; j0 += 8) {
            int src = src_next;
            {   // prefetch next batch's src before the dependent kvp load
                int enx = j0 + 8 + e;
                src_next = (enx < deg) ? srcs_s[rs + enx] : 0;
            }
            int eidx = j0 + e;
            bool valid = eidx < deg;
            int ce = valid ? eidx : 0;

            const uint4* kp = (const uint4*)(kvp + (size_t)src * 64 + h * 8);
            uint4 k0 = kp[0], k1 = kp[1];
            const uint4* ep = (const uint4*)(ea_s + (size_t)(rs + ce) * 8);
            uint4 u0 = ep[0], u1 = ep[1];

            float ex[ED];
            #pragma unroll
            for (int j = 0; j < 4; ++j) {
                ex[j * 2]         = bf_lo((&u0.x)[j]);
                ex[j * 2 + 1]     = bf_hi((&u0.x)[j]);
                ex[8 + j * 2]     = bf_lo((&u1.x)[j]);
                ex[8 + j * 2 + 1] = bf_hi((&u1.x)[j]);
            }
            float c = qbeh;
            c += (&q0.x)[0] * bf_lo(k0.x); c += (&q0.x)[1] * bf_lo(k0.y);
            c += (&q0.x)[2] * bf_lo(k0.z); c += (&q0.x)[3] * bf_lo(k0.w);
            c += (&q1.x)[0] * bf_lo(k1.x); c += (&q1.x)[1] * bf_lo(k1.y);
            c += (&q1.x)[2] * bf_lo(k1.z); c += (&q1.x)[3] * bf_lo(k1.w);
            #pragma unroll
            for (int i = 0; i < ED; ++i) c += ex[i] * a16[i];

            float p = valid ? __expf(c) : 0.f;
            den += p;
            acc[0] += p * bf_hi(k0.x); acc[1] += p * bf_hi(k0.y);
            acc[2] += p * bf_hi(k0.z); acc[3] += p * bf_hi(k0.w);
            acc[4] += p * bf_hi(k1.x); acc[5] += p * bf_hi(k1.y);
            acc[6] += p * bf_hi(k1.z); acc[7] += p * bf_hi(k1.w);
            #pragma unroll
            for (int i = 0; i < ED; ++i) sv[i] += p * ex[i];
        }

        // reduces over e-lane groups
        #pragma unroll
        for (int m = 8; m <= 32; m <<= 1) {
            den += __shfl_xor(den, m);
            #pragma unroll
            for (int i = 0; i < ED; ++i) sv[i] += __shfl_xor(sv[i], m);
        }
        float vsum = khreduce8(acc, e);

        float esum = 0.f;
        #pragma unroll
        for (int i = 0; i < ED; ++i) esum += rWe[i] * sv[i];

        float o = (vsum + esum + bev * den) / (den + 1e-16f);

        float xrv = xr[(size_t)nid * D + cmix];
        float tb  = o * wb0 + xrv * wb1 + (o - xrv) * wb2;
        #pragma unroll
        for (int s = 1; s < 64; s <<= 1) tb += __shfl_xor(tb, s);
        float g  = 1.f / (1.f + __expf(-tb));
        float o2 = g * xrv + (1.f - g) * o;
        out[(size_t)nid * D + cmix] = o2;
        s1bn += o2; s2bn += o2 * o2;
    }

    l1[w][cmix] = s1bn; l2[w][cmix] = s2bn;
    __syncthreads();
    if (threadIdx.x < D) {
        float a = l1[0][threadIdx.x] + l1[1][threadIdx.x]
                + l1[2][threadIdx.x] + l1[3][threadIdx.x];
        float b = l2[0][threadIdx.x] + l2[1][threadIdx.x]
                + l2[2][threadIdx.x] + l2[3][threadIdx.x];
        unsafeAtomicAdd(&S1p[threadIdx.x * 64], a);
        unsafeAtomicAdd(&S2p[threadIdx.x * 64], b);
    }
}

// ---------------------------------------------------------------------------
// K7: batchnorm finalize + apply + LeakyReLU, float4 in place on d_out.
// ---------------------------------------------------------------------------
__global__ __launch_bounds__(256) void bn_apply(
    float4* __restrict__ out, const float* __restrict__ S1p,
    const float* __restrict__ S2p, const float* __restrict__ gamma,
    const float* __restrict__ beta, int total4, float invN)
{
    int gid = blockIdx.x * 256 + threadIdx.x;
    if (gid >= total4) return;
    int col = (gid & 15) * 4;
    float4 g4 = *(const float4*)(gamma + col);
    float4 b4 = *(const float4*)(beta + col);
    float4 y  = out[gid];
    #pragma unroll
    for (int j = 0; j < 4; ++j) {
        float mean = S1p[(col + j) * 64] * invN;
        float var  = S2p[(col + j) * 64] * invN - mean * mean;
        float sc   = (&g4.x)[j] * rsqrtf(var + 1e-5f);
        float sh   = (&b4.x)[j] - mean * sc;
        float tv   = (&y.x)[j] * sc + sh;
        (&y.x)[j]  = (tv >= 0.f) ? tv : 0.01f * tv;
    }
    out[gid] = y;
}

// ---------------------------------------------------------------------------
extern "C" void kernel_launch(void* const* d_in, const int* in_sizes, int n_in,
                              void* d_out, int out_size, void* d_ws, size_t ws_size,
                              hipStream_t stream)
{
    const float* x     = (const float*)d_in[0];
    const int*   ei    = (const int*)  d_in[1];
    const float* ea    = (const float*)d_in[2];
    const float* Wq    = (const float*)d_in[3];
    const float* bq    = (const float*)d_in[4];
    const float* Wk    = (const float*)d_in[5];
    const float* bk    = (const float*)d_in[6];
    const float* Wv    = (const float*)d_in[7];
    const float* bv    = (const float*)d_in[8];
    const float* We    = (const float*)d_in[9];
    const float* be    = (const float*)d_in[10];
    const float* Wskip = (const float*)d_in[11];
    const float* bskip = (const float*)d_in[12];
    const float* Wbeta = (const float*)d_in[13];
    const float* gamma = (const float*)d_in[14];
    const float* betab = (const float*)d_in[15];

    int N = in_sizes[0] / D;   // 50000
    int E = in_sizes[1] / 2;   // 800000

    // ws layout (uint units); total ~82.0 MB
    int*    ws        = (int*)d_ws;
    int*    cnt       = ws;                         // 50000 (also scatter cursor)
    float*  S1p       = (float*)(ws + 50000);       // 4096 padded col sums
    float*  S2p       = (float*)(ws + 54096);       // 4096
    int*    row_start = ws + 58192;                 // 50004
    int*    bsum      = ws + 108240;                // 256 (16B aligned)
    int*    srcs_s    = ws + 108544;                // 800000
    uint_t* ea_s      = (uint_t*)(ws + 908544);     // 6400000
    uint_t* kvp       = (uint_t*)(ws + 7308544);    // 3200000
    float*  q         = (float*)(ws + 10508544);    // 3200000
    float*  xr        = (float*)(ws + 13708544);    // 3200000
    uint_t* Ap        = (uint_t*)(ws + 16908544);   // 3200000
    float*  qbe       = (float*)(ws + 20108544);    // 400000

    // zero cnt + S1p + S2p (contiguous)
    hipMemsetAsync(d_ws, 0, (size_t)58192 * sizeof(int), stream);

    int projB = (N + 63) / 64;      // 782
    int histB = (E + 255) / 256;    // 3125
    proj_qs_hist<<<projB + histB, 256, 0, stream>>>(
        x, Wq, bq, Wskip, bskip, We, be,
        q, xr, Ap, qbe, N, ei, cnt, E, projB);

    int scanB = (N + 255) / 256;    // 196
    proj_kv_scana<<<projB + scanB, 256, 0, stream>>>(
        x, Wk, bk, Wv, bv, kvp, N, projB, cnt, bsum);

    scan_c<<<scanB, 256, 0, stream>>>(cnt, bsum, row_start, cnt, N, E, scanB);

    csr_scatter<<<(E + 255) / 256, 256, 0, stream>>>(
        ei, (const float4*)ea, cnt, srcs_s, ea_s, E);

    node_gather<<<1024, 256, 0, stream>>>(
        row_start, srcs_s, ea_s, We, be, q, kvp, xr, Ap, qbe, Wbeta,
        (float*)d_out, S1p, S2p, N);

    bn_apply<<<(N * 16 + 255) / 256, 256, 0, stream>>>(
        (float4*)d_out, S1p, S2p, gamma, betab, N * 16, 1.0f / (float)N);
}